// Round 1
// baseline (172.078 us; speedup 1.0000x reference)
//
#include <hip/hip_runtime.h>
#include <stdint.h>

typedef __attribute__((ext_vector_type(8))) short short8;
typedef __attribute__((ext_vector_type(4))) float floatx4;
typedef __attribute__((ext_vector_type(2))) unsigned int uintx2;
typedef unsigned short u16;
typedef unsigned int u32;

#define EDIM 128
#define FDIM 512
#define BM 64
#define FC 256            // F processed in chunks of 256 so h-chunk fits LDS
#define QSTR (EDIM + 8)   // 136 bf16 -> 272 B row stride (16B-aligned, 2-way banks)
#define HSTR (FC + 8)     // 264 bf16 -> 528 B row stride

// round-to-nearest-even float -> bf16 (values are finite; no NaN handling needed)
__device__ __forceinline__ u32 f2bf_rne(float f) {
    u32 u = __builtin_bit_cast(u32, f);
    return (u + 0x7fffu + ((u >> 16) & 1u)) >> 16;
}
__device__ __forceinline__ u32 pk2bf(float lo, float hi) {
    return f2bf_rne(lo) | (f2bf_rne(hi) << 16);
}

// Convert W1 (512x128 f32) and W2 (128x512 f32) to bf16 into workspace.
// ws layout: [0,65536) = W1b rows f (contig e), [65536,131072) = W2b rows e (contig f).
__global__ __launch_bounds__(256) void ffq_prep(const float* __restrict__ W1,
                                                const float* __restrict__ W2,
                                                u16* __restrict__ wb) {
    int i4 = blockIdx.x * 256 + threadIdx.x;  // float4 index, 0..32767
    const float4* src = (i4 < 16384)
        ? (reinterpret_cast<const float4*>(W1) + i4)
        : (reinterpret_cast<const float4*>(W2) + (i4 - 16384));
    float4 v = *src;
    uintx2 p;
    p.x = pk2bf(v.x, v.y);
    p.y = pk2bf(v.z, v.w);
    *(reinterpret_cast<uintx2*>(wb) + i4) = p;
}

// Fused: q = cos(x)*cos(theta) -> h = relu(q @ W1^T) -> out = h @ W2^T
// One block = 64 rows of M. 8 waves. MFMA 16x16x32 bf16, fp32 accum.
// GEMM1 computes h^T tiles (A=W1, B=q with n=m)  -> D packs 4 consecutive f per lane.
// GEMM2 computes out^T tiles (A=W2, B=h)         -> D packs 4 consecutive e per lane.
__global__ __launch_bounds__(512, 4) void ffq_main(const float* __restrict__ x,
                                                   const float* __restrict__ theta,
                                                   const u16* __restrict__ wb,
                                                   float* __restrict__ out) {
    __shared__ u16 qs[BM * QSTR];   // 17408 B
    __shared__ u16 hs[BM * HSTR];   // 33792 B  (total 50 KB < 64 KB)

    const int t = threadIdx.x;
    const int lane = t & 63;
    const int wv = t >> 6;        // wave id 0..7
    const int l15 = lane & 15;
    const int quad = lane >> 4;   // 0..3

    // ---- stage q into LDS (bf16) ----
    {
        const float4* xin = reinterpret_cast<const float4*>(x) +
                            (size_t)blockIdx.x * (BM * EDIM / 4);
        const int et = (t & 31) * 4;  // e offset; constant across r since 2048 % 128 == 0
        float c0 = __cosf(theta[et + 0]);
        float c1 = __cosf(theta[et + 1]);
        float c2 = __cosf(theta[et + 2]);
        float c3 = __cosf(theta[et + 3]);
        #pragma unroll
        for (int r = 0; r < 4; ++r) {
            int i = t + 512 * r;   // float4 index within tile
            int m = i >> 5;        // row 0..63
            float4 v = xin[i];
            uintx2 p;
            p.x = pk2bf(__cosf(v.x) * c0, __cosf(v.y) * c1);
            p.y = pk2bf(__cosf(v.z) * c2, __cosf(v.w) * c3);
            *reinterpret_cast<uintx2*>(&qs[m * QSTR + et]) = p;
        }
    }
    __syncthreads();

    const u16* W1b = wb;                  // [512][128] bf16
    const u16* W2b = wb + FDIM * EDIM;    // [128][512] bf16

    floatx4 acc2[4];  // out^T tiles: e-tile = wv, m-tiles 0..3; persists across chunks
    #pragma unroll
    for (int mt = 0; mt < 4; ++mt) acc2[mt] = (floatx4){0.f, 0.f, 0.f, 0.f};

    #pragma unroll
    for (int c = 0; c < 2; ++c) {
        // ---- GEMM1: h^T tiles = W1_tile x q^T ----
        // wave wv owns f-tiles {2wv, 2wv+1} of this chunk, all 4 m-tiles
        floatx4 acc1[2][4];
        #pragma unroll
        for (int i = 0; i < 2; ++i)
            #pragma unroll
            for (int mt = 0; mt < 4; ++mt) acc1[i][mt] = (floatx4){0.f, 0.f, 0.f, 0.f};

        const int f0 = c * FC + (2 * wv) * 16;  // global W1 row of tile i=0
        #pragma unroll
        for (int k = 0; k < 4; ++k) {           // K = 128 = 4 x 32
            const int kq = k * 32 + quad * 8;
            // A-frags: W1[f0+l15][kq..kq+7] — 16B contiguous, L2-resident
            short8 a0 = *reinterpret_cast<const short8*>(
                W1b + (size_t)(f0 + l15) * EDIM + kq);
            short8 a1 = *reinterpret_cast<const short8*>(
                W1b + (size_t)(f0 + 16 + l15) * EDIM + kq);
            // B-frags: q[m0+l15][kq..kq+7] — ds_read_b128
            short8 bq[4];
            #pragma unroll
            for (int mt = 0; mt < 4; ++mt)
                bq[mt] = *reinterpret_cast<const short8*>(
                    &qs[(mt * 16 + l15) * QSTR + kq]);
            #pragma unroll
            for (int mt = 0; mt < 4; ++mt)
                acc1[0][mt] = __builtin_amdgcn_mfma_f32_16x16x32_bf16(a0, bq[mt], acc1[0][mt], 0, 0, 0);
            #pragma unroll
            for (int mt = 0; mt < 4; ++mt)
                acc1[1][mt] = __builtin_amdgcn_mfma_f32_16x16x32_bf16(a1, bq[mt], acc1[1][mt], 0, 0, 0);
        }

        __syncthreads();  // previous chunk's GEMM2 h-reads done before overwrite

        // relu + bf16(RNE) + store h[m][f_local]; lane holds 4 consecutive f -> b64 write
        #pragma unroll
        for (int i = 0; i < 2; ++i) {
            const int fl = (2 * wv + i) * 16 + quad * 4;  // f within chunk
            #pragma unroll
            for (int mt = 0; mt < 4; ++mt) {
                floatx4 v = acc1[i][mt];
                uintx2 p;
                p.x = pk2bf(fmaxf(v[0], 0.f), fmaxf(v[1], 0.f));
                p.y = pk2bf(fmaxf(v[2], 0.f), fmaxf(v[3], 0.f));
                *reinterpret_cast<uintx2*>(&hs[(mt * 16 + l15) * HSTR + fl]) = p;
            }
        }
        __syncthreads();

        // ---- GEMM2: out^T tiles += W2_tile x h^T ----
        #pragma unroll
        for (int k = 0; k < 8; ++k) {           // chunk K = 256 = 8 x 32
            const int kq = k * 32 + quad * 8;
            short8 a = *reinterpret_cast<const short8*>(
                W2b + (size_t)(wv * 16 + l15) * FDIM + c * FC + kq);
            short8 bh[4];
            #pragma unroll
            for (int mt = 0; mt < 4; ++mt)
                bh[mt] = *reinterpret_cast<const short8*>(
                    &hs[(mt * 16 + l15) * HSTR + kq]);
            #pragma unroll
            for (int mt = 0; mt < 4; ++mt)
                acc2[mt] = __builtin_amdgcn_mfma_f32_16x16x32_bf16(a, bh[mt], acc2[mt], 0, 0, 0);
        }
    }

    // ---- epilogue: out[m][e], lane holds 4 consecutive e -> float4 store ----
    float* op = out + (size_t)blockIdx.x * BM * EDIM;
    const int col = wv * 16 + quad * 4;
    #pragma unroll
    for (int mt = 0; mt < 4; ++mt) {
        *reinterpret_cast<floatx4*>(op + (mt * 16 + l15) * EDIM + col) = acc2[mt];
    }
}

extern "C" void kernel_launch(void* const* d_in, const int* in_sizes, int n_in,
                              void* d_out, int out_size, void* d_ws, size_t ws_size,
                              hipStream_t stream) {
    const float* x     = (const float*)d_in[0];  // [32,4096,128]
    const float* theta = (const float*)d_in[1];  // [128]
    const float* W1    = (const float*)d_in[2];  // [512,128]
    const float* W2    = (const float*)d_in[3];  // [128,512]
    u16* wb    = (u16*)d_ws;                     // 256 KB bf16 weights
    float* out = (float*)d_out;                  // [32,4096,128]

    ffq_prep<<<128, 256, 0, stream>>>(W1, W2, wb);
    ffq_main<<<2048, 512, 0, stream>>>(x, theta, wb, out);
}